// Round 1
// baseline (51.689 us; speedup 1.0000x reference)
//
#include <hip/hip_runtime.h>

#define UNITS 4096
#define BATCH 8192

// Extract diag(w) into a compact array (16 KiB) so the hot kernel's
// per-column scale factors are contiguous and cache-resident.
__global__ void extract_diag_kernel(const float* __restrict__ w,
                                    float* __restrict__ diag) {
    int j = blockIdx.x * blockDim.x + threadIdx.x;
    if (j < UNITS) {
        diag[j] = w[(size_t)j * (UNITS + 1)];
    }
}

// out[b,j] = x[b,j] * diag[j]; float4-vectorized, grid-stride.
__global__ void __launch_bounds__(256)
diag_scale_kernel(const float* __restrict__ x,
                  const float* __restrict__ diag,
                  float* __restrict__ out) {
    const int n4 = (BATCH * UNITS) / 4;           // 8,388,608 float4s
    const float4* __restrict__ x4 = (const float4*)x;
    const float4* __restrict__ d4 = (const float4*)diag;
    float4* __restrict__ o4 = (float4*)out;

    for (int i = blockIdx.x * blockDim.x + threadIdx.x; i < n4;
         i += gridDim.x * blockDim.x) {
        int c = i & (UNITS / 4 - 1);              // column group (1024 per row)
        float4 xv = x4[i];
        float4 dv = d4[c];
        float4 ov;
        ov.x = xv.x * dv.x;
        ov.y = xv.y * dv.y;
        ov.z = xv.z * dv.z;
        ov.w = xv.w * dv.w;
        o4[i] = ov;
    }
}

extern "C" void kernel_launch(void* const* d_in, const int* in_sizes, int n_in,
                              void* d_out, int out_size, void* d_ws, size_t ws_size,
                              hipStream_t stream) {
    const float* x = (const float*)d_in[0];
    const float* w = (const float*)d_in[1];
    float* out = (float*)d_out;
    float* diag = (float*)d_ws;                   // 4096 floats = 16 KiB

    extract_diag_kernel<<<(UNITS + 255) / 256, 256, 0, stream>>>(w, diag);

    const int blocks = 2048;                      // ~8 blocks/CU, grid-stride
    diag_scale_kernel<<<blocks, 256, 0, stream>>>(x, diag, out);
}